// Round 7
// baseline (105.406 us; speedup 1.0000x reference)
//
#include <hip/hip_runtime.h>
#include <math.h>

#define IMG    256
#define NPTS   320
#define CHUNKS 8
#define NBLK   1024        // 32x32 tiles of 8x8 pixels
#define NXCD   8

// 8-byte load valid at 4-byte alignment (lowers to dwordx2 or 2x dword).
struct f2 { float lo, hi; };
__device__ __forceinline__ f2 ld2(const float* p) {
    f2 r; __builtin_memcpy(&r, p, 8); return r;
}

// ---------------------------------------------------------------------------
// Render: block = 8x8 pixel tile x 8 depth chunks (512 thr) — round-1's
// proven wave layout (one wave = whole tile at one depth window -> tight
// gather neighborhood). Three fixes composed on top:
//  * XCD swizzle (R5/R6-proven: FETCH 220->54/70 MB).
//  * __launch_bounds__(512,2): lifts the VGPR cap 64->128 so the batch-4
//    interior actually materializes (R4 with default bounds got VGPR=32 and
//    serialized every pair-load -> 129 us; R3 at 256thr/VGPR=44 proved the
//    batch raises VALUBusy when registers exist).
//  * per-PIXEL balanced chunk split: chunk c = c-th eighth of THIS pixel's
//    clipped range (transmittance composition is valid for any ordered
//    contiguous partition) -> all 8 waves of a live tile get equal work
//    (round 1-6: fixed windows left 5-6 of 8 waves empty -> occupancy 41%).
// ---------------------------------------------------------------------------
__global__ __launch_bounds__(512, 2)
void xray_render(const float* __restrict__ vol,
                 const float* __restrict__ Rm,
                 const float* __restrict__ Tv,
                 const float* __restrict__ fc,
                 float* __restrict__ outv,
                 float* __restrict__ partials)
{
    // XCD-aware swizzle (1024 blocks, 1024 % 8 == 0 -> bijective):
    // each XCD owns a contiguous 256x32-pixel band (4 tile-rows).
    const int bid  = blockIdx.x;
    const int tile = (bid & (NXCD - 1)) * (NBLK / NXCD) + (bid >> 3);
    const int bx   = tile & 31;
    const int by   = tile >> 5;

    const int tid = threadIdx.x;
    const int p   = tid & 63;        // pixel within 8x8 tile
    const int c   = tid >> 6;        // depth chunk 0..7
    const int w   = (bx << 3) + (p & 7);
    const int h   = (by << 3) + (p >> 3);

    const float f   = fc[0];
    const float r00 = Rm[0], r01 = Rm[1], r02 = Rm[2];
    const float r10 = Rm[3], r11 = Rm[4], r12 = Rm[5];
    const float r20 = Rm[6], r21 = Rm[7], r22 = Rm[8];
    const float t0  = Tv[0], t1  = Tv[1], t2  = Tv[2];

    // xs[w] = 255/256 - w/128 ; ys[h] likewise
    const float invf = 1.0f / f;
    const float px = 0.99609375f - (float)w * 0.0078125f;
    const float py = 0.99609375f - (float)h * 0.0078125f;
    const float dcx = px * invf, dcy = py * invf;   // cam dir = (dcx,dcy,1)*d

    // world(d) = R @ (cam - T) = d * (R@dir) - R@T
    const float dwx = r00*dcx + r01*dcy + r02;
    const float dwy = r10*dcx + r11*dcy + r12;
    const float dwz = r20*dcx + r21*dcy + r22;
    const float ox  = -(r00*t0 + r01*t1 + r02*t2);
    const float oy  = -(r10*t0 + r11*t1 + r12*t2);
    const float oz  = -(r20*t0 + r21*t1 + r22*t2);

    // grid coords: g = 128*world + 127.5 ; depths d_i = 3 + i*(6/319)
    const float g0x = fmaf(384.0f, dwx, fmaf(128.0f, ox, 127.5f));
    const float g0y = fmaf(384.0f, dwy, fmaf(128.0f, oy, 127.5f));
    const float g0z = fmaf(384.0f, dwz, fmaf(128.0f, oz, 127.5f));
    const float K   = 768.0f / 319.0f;   // 128 * 6/319
    const float gsx = K*dwx, gsy = K*dwy, gsz = K*dwz;

    // clip ranges:
    //   coverage > 0    where g in (-1, 256) on every axis      -> [raylo, rayhi]
    //   strict interior where g in [eps, 255-eps] on every axis -> [inlo,  inhi]
    float raylo = -1e30f, rayhi = 1e30f;
    float inlo  = -1e30f, inhi  = 1e30f;
    {
        const float g0a[3] = {g0x, g0y, g0z};
        const float gsa[3] = {gsx, gsy, gsz};
        #pragma unroll
        for (int a = 0; a < 3; ++a) {
            const float g0 = g0a[a], gs = gsa[a];
            if (fabsf(gs) > 1e-6f) {
                const float r = 1.0f / gs;
                const float u = (-1.0f  - g0) * r;
                const float v = (256.0f - g0) * r;
                raylo = fmaxf(raylo, fminf(u, v));
                rayhi = fminf(rayhi, fmaxf(u, v));
                const float s = (0.001f   - g0) * r;
                const float t = (254.999f - g0) * r;
                inlo = fmaxf(inlo, fminf(s, t));
                inhi = fminf(inhi, fmaxf(s, t));
            } else {
                if (!(g0 > -1.0f && g0 < 256.0f))        { raylo = 1e30f; rayhi = -1e30f; }
                if (!(g0 > 0.001f && g0 < 254.999f))     { inlo  = 1e30f; inhi  = -1e30f; }
            }
        }
    }
    // FULL-ray sample range with 1-sample safety margin, clamped to [0,319]
    float a0 = fminf(fmaxf(raylo - 1.0f, 0.0f),  400.0f);
    float a1 = fminf(fmaxf(fminf(rayhi + 1.0f, (float)(NPTS - 1)), -1.0f), 400.0f);
    const int i0 = (int)ceilf(a0);
    const int i1 = (int)floorf(a1);
    const int len = max(0, i1 - i0 + 1);

    // this chunk = c-th eighth of THIS pixel's range (balanced split)
    const int s0 = i0 + ((len * c) >> 3);
    const int s1 = i0 + ((len * (c + 1)) >> 3) - 1;

    // interior range on the full ray; clamp before int-cast to avoid UB
    float b0 = fminf(fmaxf(inlo, (float)i0), 401.0f);
    float b1 = fmaxf(fminf(inhi, (float)i1), -2.0f);
    const int jLo = (int)ceilf(b0);
    const int jHi = (int)floorf(b1);

    float feat = 0.0f, Tc = 1.0f;   // Tc == opacity-product (identical in fp32)

    // general masked step (boundary shell; also correct for interior points)
    auto bstep = [&](int i) {
        const float fi = (float)i;
        const float gx = fmaf(fi, gsx, g0x);
        const float gy = fmaf(fi, gsy, g0y);
        const float gz = fmaf(fi, gsz, g0z);
        const float xf = floorf(gx), yf = floorf(gy), zf = floorf(gz);
        const float fx = gx - xf, fy = gy - yf, fz = gz - zf;
        const int ix = (int)xf, iy = (int)yf, iz = (int)zf;
        const float wx0 = (ix >= 0  && ix <= 255) ? (1.0f - fx) : 0.0f;
        const float wx1 = (ix >= -1 && ix <= 254) ? fx          : 0.0f;
        const float wy0 = (iy >= 0  && iy <= 255) ? (1.0f - fy) : 0.0f;
        const float wy1 = (iy >= -1 && iy <= 254) ? fy          : 0.0f;
        const float wz0 = (iz >= 0  && iz <= 255) ? (1.0f - fz) : 0.0f;
        const float wz1 = (iz >= -1 && iz <= 254) ? fz          : 0.0f;
        const float cov = (wx0 + wx1) * (wy0 + wy1) * (wz0 + wz1);
        if (cov > 0.0f) {
            const int x0 = min(max(ix, 0), 255),   x1 = min(max(ix + 1, 0), 255);
            const int y0 = min(max(iy, 0), 255),   y1 = min(max(iy + 1, 0), 255);
            const int z0 = min(max(iz, 0), 255),   z1 = min(max(iz + 1, 0), 255);
            const float* bz0 = vol + (z0 << 16);
            const float* bz1 = vol + (z1 << 16);
            const int ry0 = y0 << 8, ry1 = y1 << 8;
            const float s0v = (bz0[ry0 + x0]*wx0 + bz0[ry0 + x1]*wx1) * wy0
                            + (bz0[ry1 + x0]*wx0 + bz0[ry1 + x1]*wx1) * wy1;
            const float s1v = (bz1[ry0 + x0]*wx0 + bz1[ry0 + x1]*wx1) * wy0
                            + (bz1[ry1 + x0]*wx0 + bz1[ry1 + x1]*wx1) * wy1;
            const float gray = s0v * wz0 + s1v * wz1;
            const float dens = 0.1f * cov;
            feat = fmaf(dens * Tc, gray, feat);
            Tc *= (1.0f - dens);
        }
    };

    // single interior sample (cov == 1, dens == 0.1): 4 pair-loads
    auto istep = [&](int i) {
        const float fi = (float)i;
        const float gx = fmaf(fi, gsx, g0x);
        const float gy = fmaf(fi, gsy, g0y);
        const float gz = fmaf(fi, gsz, g0z);
        const int ix = (int)gx, iy = (int)gy, iz = (int)gz;  // g>=0: trunc==floor
        const float fx = gx - (float)ix;
        const float fy = gy - (float)iy;
        const float fz = gz - (float)iz;
        const float* b = vol + ((iz << 16) + (iy << 8) + ix);
        const f2 a00 = ld2(b);
        const f2 a01 = ld2(b + 256);
        const f2 a10 = ld2(b + 65536);
        const f2 a11 = ld2(b + 65792);
        const float c00 = fmaf(fx, a00.hi - a00.lo, a00.lo);
        const float c01 = fmaf(fx, a01.hi - a01.lo, a01.lo);
        const float c10 = fmaf(fx, a10.hi - a10.lo, a10.lo);
        const float c11 = fmaf(fx, a11.hi - a11.lo, a11.lo);
        const float d0  = fmaf(fy, c01 - c00, c00);
        const float d1  = fmaf(fy, c11 - c10, c10);
        const float gray = fmaf(fz, d1 - d0, d0);
        feat = fmaf(0.1f * Tc, gray, feat);
        Tc *= 0.9f;
    };

    if (jLo <= jHi) {
        // boundary prefix of this chunk's share
        const int pe = min(s1, jLo - 1);
        for (int i = s0; i <= pe; ++i) bstep(i);

        // batched interior: 4 samples/group, all 16 pair-loads issued before
        // any compute -> explicit memory-level parallelism
        const int fs = max(s0, jLo), fe = min(s1, jHi);
        int i = fs;
        for (; i + 3 <= fe; i += 4) {
            float fx[4], fy[4], fz[4];
            int off[4];
            #pragma unroll
            for (int k = 0; k < 4; ++k) {
                const float fi = (float)(i + k);
                const float gx = fmaf(fi, gsx, g0x);
                const float gy = fmaf(fi, gsy, g0y);
                const float gz = fmaf(fi, gsz, g0z);
                const int ix = (int)gx, iy = (int)gy, iz = (int)gz;
                fx[k] = gx - (float)ix;
                fy[k] = gy - (float)iy;
                fz[k] = gz - (float)iz;
                off[k] = (iz << 16) + (iy << 8) + ix;
            }
            f2 a00[4], a01[4], a10[4], a11[4];
            #pragma unroll
            for (int k = 0; k < 4; ++k) {
                const float* b = vol + off[k];
                a00[k] = ld2(b);
                a01[k] = ld2(b + 256);
                a10[k] = ld2(b + 65536);
                a11[k] = ld2(b + 65792);
            }
            #pragma unroll
            for (int k = 0; k < 4; ++k) {
                const float c00 = fmaf(fx[k], a00[k].hi - a00[k].lo, a00[k].lo);
                const float c01 = fmaf(fx[k], a01[k].hi - a01[k].lo, a01[k].lo);
                const float c10 = fmaf(fx[k], a10[k].hi - a10[k].lo, a10[k].lo);
                const float c11 = fmaf(fx[k], a11[k].hi - a11[k].lo, a11[k].lo);
                const float d0  = fmaf(fy[k], c01 - c00, c00);
                const float d1  = fmaf(fy[k], c11 - c10, c10);
                const float gray = fmaf(fz[k], d1 - d0, d0);
                feat = fmaf(0.1f * Tc, gray, feat);
                Tc *= 0.9f;
            }
        }
        for (; i <= fe; ++i) istep(i);

        // boundary suffix of this chunk's share
        for (int i = max(s0, jHi + 1); i <= s1; ++i) bstep(i);
    } else {
        for (int i = s0; i <= s1; ++i) bstep(i);
    }

    // combine the 8 depth chunks per pixel (ascending-depth partition):
    // feat = f0 + T0*(f1 + T1*(f2 + ...)),  T = T0*T1*...
    __shared__ float sf[CHUNKS][64];
    __shared__ float sT[CHUNKS][64];
    sf[c][p] = feat; sT[c][p] = Tc;
    __syncthreads();

    if (tid < 64) {
        float F = sf[CHUNKS - 1][p];
        #pragma unroll
        for (int j = CHUNKS - 2; j >= 0; --j) F = fmaf(sT[j][p], F, sf[j][p]);
        float PR = sT[0][p];
        #pragma unroll
        for (int j = 1; j < CHUNKS; ++j) PR *= sT[j][p];

        const float screen = fmaf(3.0f, F, 1.0f - PR) * 0.25f;
        outv[(w << 8) + h] = screen;   // transposed output layout

        float s = screen, s2 = screen * screen, mn = screen, mx = screen;
        #pragma unroll
        for (int o = 32; o; o >>= 1) {
            s  += __shfl_xor(s,  o);
            s2 += __shfl_xor(s2, o);
            mn  = fminf(mn, __shfl_xor(mn, o));
            mx  = fmaxf(mx, __shfl_xor(mx, o));
        }
        if (p == 0) {
            float4* out4 = (float4*)partials;
            out4[bid] = make_float4(s, s2, mn, mx);
        }
    }
}

// ---------------------------------------------------------------------------
// Normalize (finalize fused): every block redundantly reduces the 1024 block
// partials (16 KB, L2-hit) to {sum,sumsq,min,max}, derives the affine, and
// normalizes its 256 pixels.  out = (v - off) / (vmax - off),
// off = vmin - 1e-8*(std+1e-8)   (the mean cancels algebraically)
// ---------------------------------------------------------------------------
__global__ __launch_bounds__(256)
void xray_normalize(float* __restrict__ outv, const float* __restrict__ partials)
{
    const int t = threadIdx.x;
    const float4* p4 = (const float4*)partials;
    double s = 0.0, s2 = 0.0;
    float mn = 1e30f, mx = -1e30f;
    #pragma unroll
    for (int j = 0; j < NBLK / 256; ++j) {
        const float4 v = p4[j * 256 + t];
        s  += (double)v.x;
        s2 += (double)v.y;
        mn  = fminf(mn, v.z);
        mx  = fmaxf(mx, v.w);
    }
    #pragma unroll
    for (int o = 32; o; o >>= 1) {
        s  += __shfl_xor(s,  o);
        s2 += __shfl_xor(s2, o);
        mn  = fminf(mn, __shfl_xor(mn, o));
        mx  = fmaxf(mx, __shfl_xor(mx, o));
    }
    __shared__ double ls[4], ls2[4];
    __shared__ float  lmn[4], lmx[4];
    __shared__ float  soff, sinv;
    const int wid = t >> 6, lane = t & 63;
    if (lane == 0) { ls[wid] = s; ls2[wid] = s2; lmn[wid] = mn; lmx[wid] = mx; }
    __syncthreads();
    if (t == 0) {
        const double S  = ls[0] + ls[1] + ls[2] + ls[3];
        const double S2 = ls2[0] + ls2[1] + ls2[2] + ls2[3];
        const float MN = fminf(fminf(lmn[0], lmn[1]), fminf(lmn[2], lmn[3]));
        const float MX = fmaxf(fmaxf(lmx[0], lmx[1]), fmaxf(lmx[2], lmx[3]));
        double var = (S2 - S * S / 65536.0) / 65535.0;
        if (var < 0.0) var = 0.0;
        const double sdp = sqrt(var) + 1e-8;
        const float off = MN - (float)(1e-8 * sdp);
        soff = off;
        sinv = 1.0f / (MX - off);
    }
    __syncthreads();
    const int i = blockIdx.x * 256 + t;
    outv[i] = (outv[i] - soff) * sinv;
}

// ---------------------------------------------------------------------------
extern "C" void kernel_launch(void* const* d_in, const int* in_sizes, int n_in,
                              void* d_out, int out_size, void* d_ws, size_t ws_size,
                              hipStream_t stream)
{
    const float* vol = (const float*)d_in[0];   // (1,1,256,256,256)
    const float* Rm  = (const float*)d_in[1];   // (1,3,3)
    const float* Tv  = (const float*)d_in[2];   // (1,3)
    const float* fc  = (const float*)d_in[3];   // (1,)
    float* outv = (float*)d_out;                // (1,1,256,256) fp32
    float* partials = (float*)d_ws;             // 1024 float4

    xray_render<<<NBLK, 512, 0, stream>>>(vol, Rm, Tv, fc, outv, partials);
    xray_normalize<<<IMG * IMG / 256, 256, 0, stream>>>(outv, partials);
}

// Round 8
// 74.456 us; speedup vs baseline: 1.4157x; 1.4157x over previous
//
#include <hip/hip_runtime.h>
#include <math.h>

#define IMG    256
#define NPTS   320
#define CHUNKS 8
#define PX     32          // pixels per tile (8 wide x 4 high)
#define NBLK   2048        // 32x64 tiles of 8x4 pixels
// block = 256 thr = 32 px x 8 chunks; grid = 2048 -> 8 blocks/CU pooled.
// No XCD swizzle: the cube projects to the image center, so any contiguous
// band->XCD mapping starves 5 of 8 XCDs (R5-R7: FETCH halved but dur +40%).
// Default round-robin dispatch balances XCDs for center-heavy work.

// ---------------------------------------------------------------------------
// Render. Body identical to the 66us round-2 kernel (per-sample if(inside)
// fast path, scalar loads, VGPR ~28). Only the WORK DISTRIBUTION changed:
//  * chunk c = c-th eighth of THIS pixel's clipped sample range (the
//    transmittance fold is valid for any ordered contiguous partition), so
//    all 8 chunk-waves of a live tile retire together (fixed windows left
//    ~5 of 8 waves empty -> occupancy 41%, retire-with-no-backfill).
//  * 8x4-px tiles / 256-thr blocks: 8 blocks pooled per CU (was 4) halves
//    CU-level work variance.
// ---------------------------------------------------------------------------
__global__ __launch_bounds__(256)
void xray_render(const float* __restrict__ vol,
                 const float* __restrict__ Rm,
                 const float* __restrict__ Tv,
                 const float* __restrict__ fc,
                 float* __restrict__ outv,
                 float* __restrict__ partials)
{
    const int bid = blockIdx.x;
    const int bx  = bid & 31;        // 32 tiles across (8 px each)
    const int by  = bid >> 5;        // 64 tiles down   (4 px each)

    const int tid = threadIdx.x;
    const int p   = tid & 31;        // pixel within 8x4 tile
    const int c   = tid >> 5;        // depth chunk 0..7
    const int w   = (bx << 3) + (p & 7);
    const int h   = (by << 2) + (p >> 3);

    const float f   = fc[0];
    const float r00 = Rm[0], r01 = Rm[1], r02 = Rm[2];
    const float r10 = Rm[3], r11 = Rm[4], r12 = Rm[5];
    const float r20 = Rm[6], r21 = Rm[7], r22 = Rm[8];
    const float t0  = Tv[0], t1  = Tv[1], t2  = Tv[2];

    // xs[w] = 255/256 - w/128 ; ys[h] likewise
    const float invf = 1.0f / f;
    const float px = 0.99609375f - (float)w * 0.0078125f;
    const float py = 0.99609375f - (float)h * 0.0078125f;
    const float dcx = px * invf, dcy = py * invf;   // cam dir = (dcx,dcy,1)*d

    // world(d) = R @ (cam - T) = d * (R@dir) - R@T
    const float dwx = r00*dcx + r01*dcy + r02;
    const float dwy = r10*dcx + r11*dcy + r12;
    const float dwz = r20*dcx + r21*dcy + r22;
    const float ox  = -(r00*t0 + r01*t1 + r02*t2);
    const float oy  = -(r10*t0 + r11*t1 + r12*t2);
    const float oz  = -(r20*t0 + r21*t1 + r22*t2);

    // grid coords: g = 128*world + 127.5 ; depths d_i = 3 + i*(6/319)
    const float g0x = fmaf(384.0f, dwx, fmaf(128.0f, ox, 127.5f));
    const float g0y = fmaf(384.0f, dwy, fmaf(128.0f, oy, 127.5f));
    const float g0z = fmaf(384.0f, dwz, fmaf(128.0f, oz, 127.5f));
    const float K   = 768.0f / 319.0f;   // 128 * 6/319
    const float gsx = K*dwx, gsy = K*dwy, gsz = K*dwz;

    // ray-box clip: coverage > 0 only where g in (-1, 256) on every axis
    float raylo = -1e30f, rayhi = 1e30f;
    {
        const float g0a[3] = {g0x, g0y, g0z};
        const float gsa[3] = {gsx, gsy, gsz};
        #pragma unroll
        for (int a = 0; a < 3; ++a) {
            if (fabsf(gsa[a]) > 1e-9f) {
                float u = (-1.0f  - g0a[a]) / gsa[a];
                float v = (256.0f - g0a[a]) / gsa[a];
                raylo = fmaxf(raylo, fminf(u, v));
                rayhi = fminf(rayhi, fmaxf(u, v));
            } else if (!(g0a[a] > -1.0f && g0a[a] < 256.0f)) {
                raylo = 1e30f; rayhi = -1e30f;
            }
        }
    }
    // 1-sample safety margin, clamp to [0, 319]; then this pixel's range is
    // split into 8 equal eighths -- chunk c walks the c-th eighth.
    float a0 = fminf(fmaxf(raylo - 1.0f, 0.0f),  400.0f);
    float a1 = fminf(fmaxf(fminf(rayhi + 1.0f, (float)(NPTS - 1)), -1.0f), 400.0f);
    const int i0  = (int)ceilf(a0);
    const int i1  = (int)floorf(a1);
    const int len = max(0, i1 - i0 + 1);
    const int s0  = i0 + ((len * c) >> 3);
    const int s1  = i0 + ((len * (c + 1)) >> 3) - 1;

    float feat = 0.0f, Tc = 1.0f;   // Tc doubles as the opacity product (fp32-identical)

    for (int i = s0; i <= s1; ++i) {
        const float fi = (float)i;
        const float gx = fmaf(fi, gsx, g0x);
        const float gy = fmaf(fi, gsy, g0y);
        const float gz = fmaf(fi, gsz, g0z);
        const float xf = floorf(gx), yf = floorf(gy), zf = floorf(gz);
        const float fx = gx - xf, fy = gy - yf, fz = gz - zf;
        const int ix = (int)xf, iy = (int)yf, iz = (int)zf;

        if ((unsigned)ix <= 254u && (unsigned)iy <= 254u && (unsigned)iz <= 254u) {
            // fully inside: coverage == 1, dens == 0.1 exactly
            const float* b = vol + ((iz << 16) + (iy << 8) + ix);
            const float v000 = b[0],     v001 = b[1];
            const float v010 = b[256],   v011 = b[257];
            const float v100 = b[65536], v101 = b[65537];
            const float v110 = b[65792], v111 = b[65793];
            const float c00 = fmaf(fx, v001 - v000, v000);
            const float c01 = fmaf(fx, v011 - v010, v010);
            const float c10 = fmaf(fx, v101 - v100, v100);
            const float c11 = fmaf(fx, v111 - v110, v110);
            const float c0  = fmaf(fy, c01 - c00, c00);
            const float c1  = fmaf(fy, c11 - c10, c10);
            const float gray = fmaf(fz, c1 - c0, c0);
            feat = fmaf(0.1f * Tc, gray, feat);
            Tc *= 0.9f;
        } else {
            // boundary shell: masked weights, clamped indices
            const float wx0 = (ix >= 0  && ix <= 255) ? (1.0f - fx) : 0.0f;
            const float wx1 = (ix >= -1 && ix <= 254) ? fx          : 0.0f;
            const float wy0 = (iy >= 0  && iy <= 255) ? (1.0f - fy) : 0.0f;
            const float wy1 = (iy >= -1 && iy <= 254) ? fy          : 0.0f;
            const float wz0 = (iz >= 0  && iz <= 255) ? (1.0f - fz) : 0.0f;
            const float wz1 = (iz >= -1 && iz <= 254) ? fz          : 0.0f;
            const float cov = (wx0 + wx1) * (wy0 + wy1) * (wz0 + wz1);
            if (cov > 0.0f) {
                const int x0 = min(max(ix, 0), 255),   x1 = min(max(ix + 1, 0), 255);
                const int y0 = min(max(iy, 0), 255),   y1 = min(max(iy + 1, 0), 255);
                const int z0 = min(max(iz, 0), 255),   z1 = min(max(iz + 1, 0), 255);
                const float* bz0 = vol + (z0 << 16);
                const float* bz1 = vol + (z1 << 16);
                const int ry0 = y0 << 8, ry1 = y1 << 8;
                const float sv0 = (bz0[ry0 + x0]*wx0 + bz0[ry0 + x1]*wx1) * wy0
                                + (bz0[ry1 + x0]*wx0 + bz0[ry1 + x1]*wx1) * wy1;
                const float sv1 = (bz1[ry0 + x0]*wx0 + bz1[ry0 + x1]*wx1) * wy0
                                + (bz1[ry1 + x0]*wx0 + bz1[ry1 + x1]*wx1) * wy1;
                const float gray = sv0 * wz0 + sv1 * wz1;
                const float dens = 0.1f * cov;
                feat = fmaf(dens * Tc, gray, feat);
                Tc *= (1.0f - dens);
            }
        }
    }

    // combine the 8 depth chunks per pixel (ascending-depth partition):
    // feat = f0 + T0*(f1 + T1*(f2 + ...)),  T = T0*T1*...
    __shared__ float sf[CHUNKS][PX];
    __shared__ float sT[CHUNKS][PX];
    sf[c][p] = feat; sT[c][p] = Tc;
    __syncthreads();

    if (tid < PX) {
        float F = sf[CHUNKS - 1][p];
        #pragma unroll
        for (int j = CHUNKS - 2; j >= 0; --j) F = fmaf(sT[j][p], F, sf[j][p]);
        float PR = sT[0][p];
        #pragma unroll
        for (int j = 1; j < CHUNKS; ++j) PR *= sT[j][p];

        const float screen = fmaf(3.0f, F, 1.0f - PR) * 0.25f;
        outv[(w << 8) + h] = screen;   // transposed output layout

        float s = screen, s2 = screen * screen, mn = screen, mx = screen;
        #pragma unroll
        for (int o = 16; o; o >>= 1) {          // reduce across 32 lanes
            s  += __shfl_xor(s,  o);
            s2 += __shfl_xor(s2, o);
            mn  = fminf(mn, __shfl_xor(mn, o));
            mx  = fmaxf(mx, __shfl_xor(mx, o));
        }
        if (p == 0) {
            float4* out4 = (float4*)partials;
            out4[bid] = make_float4(s, s2, mn, mx);
        }
    }
}

// ---------------------------------------------------------------------------
// Normalize (finalize fused): every block redundantly reduces the 2048 block
// partials (32 KB, L2-hit) to {sum,sumsq,min,max}, derives the affine, and
// normalizes its 256 pixels.  out = (v - off) / (vmax - off),
// off = vmin - 1e-8*(std+1e-8)   (the mean cancels algebraically)
// ---------------------------------------------------------------------------
__global__ __launch_bounds__(256)
void xray_normalize(float* __restrict__ outv, const float* __restrict__ partials)
{
    const int t = threadIdx.x;
    const float4* p4 = (const float4*)partials;
    double s = 0.0, s2 = 0.0;
    float mn = 1e30f, mx = -1e30f;
    #pragma unroll
    for (int j = 0; j < NBLK / 256; ++j) {
        const float4 v = p4[j * 256 + t];
        s  += (double)v.x;
        s2 += (double)v.y;
        mn  = fminf(mn, v.z);
        mx  = fmaxf(mx, v.w);
    }
    #pragma unroll
    for (int o = 32; o; o >>= 1) {
        s  += __shfl_xor(s,  o);
        s2 += __shfl_xor(s2, o);
        mn  = fminf(mn, __shfl_xor(mn, o));
        mx  = fmaxf(mx, __shfl_xor(mx, o));
    }
    __shared__ double ls[4], ls2[4];
    __shared__ float  lmn[4], lmx[4];
    __shared__ float  soff, sinv;
    const int wid = t >> 6, lane = t & 63;
    if (lane == 0) { ls[wid] = s; ls2[wid] = s2; lmn[wid] = mn; lmx[wid] = mx; }
    __syncthreads();
    if (t == 0) {
        const double S  = ls[0] + ls[1] + ls[2] + ls[3];
        const double S2 = ls2[0] + ls2[1] + ls2[2] + ls2[3];
        const float MN = fminf(fminf(lmn[0], lmn[1]), fminf(lmn[2], lmn[3]));
        const float MX = fmaxf(fmaxf(lmx[0], lmx[1]), fmaxf(lmx[2], lmx[3]));
        double var = (S2 - S * S / 65536.0) / 65535.0;
        if (var < 0.0) var = 0.0;
        const double sdp = sqrt(var) + 1e-8;
        const float off = MN - (float)(1e-8 * sdp);
        soff = off;
        sinv = 1.0f / (MX - off);
    }
    __syncthreads();
    const int i = blockIdx.x * 256 + t;
    outv[i] = (outv[i] - soff) * sinv;
}

// ---------------------------------------------------------------------------
extern "C" void kernel_launch(void* const* d_in, const int* in_sizes, int n_in,
                              void* d_out, int out_size, void* d_ws, size_t ws_size,
                              hipStream_t stream)
{
    const float* vol = (const float*)d_in[0];   // (1,1,256,256,256)
    const float* Rm  = (const float*)d_in[1];   // (1,3,3)
    const float* Tv  = (const float*)d_in[2];   // (1,3)
    const float* fc  = (const float*)d_in[3];   // (1,)
    float* outv = (float*)d_out;                // (1,1,256,256) fp32
    float* partials = (float*)d_ws;             // 2048 float4

    xray_render<<<NBLK, 256, 0, stream>>>(vol, Rm, Tv, fc, outv, partials);
    xray_normalize<<<IMG * IMG / 256, 256, 0, stream>>>(outv, partials);
}

// Round 9
// 72.310 us; speedup vs baseline: 1.4577x; 1.0297x over previous
//
#include <hip/hip_runtime.h>
#include <math.h>

#define IMG    256
#define NPTS   320
#define CHUNKS 16
#define PX     32          // pixels per tile (8 wide x 4 high)
#define NBLK   2048        // 32x64 tiles of 8x4 pixels
// block = 512 thr = 32 px x 16 chunks -> cap 4 resident blocks/CU (2048 thr),
// grid 2048 = 8 blocks/CU total -> 2x OVERSUBSCRIBED: retiring blocks are
// backfilled (R2/R8: grid exactly filled the machine -> no backfill,
// occupancy 35-41% = CU duty cycle, corner-tile CUs idle).
// Blocks are ordered CENTER-OUT (cube projects to image center): heavy tiles
// dispatch first, empty corner tiles pad the tail (LPT scheduling).
// No XCD swizzle (R5-R7: contiguous bands starve 5 of 8 XCDs).

// ---------------------------------------------------------------------------
// Render. Per-sample body identical to the proven round-2/8 kernel (scalar
// loads, if(inside) fast path, VGPR ~24; R5-R7 showed batching/pipelining
// attempts only poison codegen). Chunk c walks the c-th sixteenth of THIS
// pixel's clipped range (transmittance folds over any ordered partition).
// ---------------------------------------------------------------------------
__global__ __launch_bounds__(512)
void xray_render(const float* __restrict__ vol,
                 const float* __restrict__ Rm,
                 const float* __restrict__ Tv,
                 const float* __restrict__ fc,
                 float* __restrict__ outv,
                 float* __restrict__ partials)
{
    // center-out tile order: low bid -> image-center tile (dispatched first)
    const int bid = blockIdx.x;
    const int r   = bid >> 5;        // 0..63  (tile row rank)
    const int q   = bid & 31;        // 0..31  (tile col rank)
    const int by  = (r & 1) ? (31 - (r >> 1)) : (32 + (r >> 1));   // 0..63
    const int bx  = (q & 1) ? (15 - (q >> 1)) : (16 + (q >> 1));   // 0..31

    const int tid = threadIdx.x;
    const int p   = tid & 31;        // pixel within 8x4 tile
    const int c   = tid >> 5;        // depth chunk 0..15
    const int w   = (bx << 3) + (p & 7);
    const int h   = (by << 2) + (p >> 3);

    const float f   = fc[0];
    const float r00 = Rm[0], r01 = Rm[1], r02 = Rm[2];
    const float r10 = Rm[3], r11 = Rm[4], r12 = Rm[5];
    const float r20 = Rm[6], r21 = Rm[7], r22 = Rm[8];
    const float t0  = Tv[0], t1  = Tv[1], t2  = Tv[2];

    // xs[w] = 255/256 - w/128 ; ys[h] likewise
    const float invf = 1.0f / f;
    const float px = 0.99609375f - (float)w * 0.0078125f;
    const float py = 0.99609375f - (float)h * 0.0078125f;
    const float dcx = px * invf, dcy = py * invf;   // cam dir = (dcx,dcy,1)*d

    // world(d) = R @ (cam - T) = d * (R@dir) - R@T
    const float dwx = r00*dcx + r01*dcy + r02;
    const float dwy = r10*dcx + r11*dcy + r12;
    const float dwz = r20*dcx + r21*dcy + r22;
    const float ox  = -(r00*t0 + r01*t1 + r02*t2);
    const float oy  = -(r10*t0 + r11*t1 + r12*t2);
    const float oz  = -(r20*t0 + r21*t1 + r22*t2);

    // grid coords: g = 128*world + 127.5 ; depths d_i = 3 + i*(6/319)
    const float g0x = fmaf(384.0f, dwx, fmaf(128.0f, ox, 127.5f));
    const float g0y = fmaf(384.0f, dwy, fmaf(128.0f, oy, 127.5f));
    const float g0z = fmaf(384.0f, dwz, fmaf(128.0f, oz, 127.5f));
    const float K   = 768.0f / 319.0f;   // 128 * 6/319
    const float gsx = K*dwx, gsy = K*dwy, gsz = K*dwz;

    // ray-box clip: coverage > 0 only where g in (-1, 256) on every axis
    float raylo = -1e30f, rayhi = 1e30f;
    {
        const float g0a[3] = {g0x, g0y, g0z};
        const float gsa[3] = {gsx, gsy, gsz};
        #pragma unroll
        for (int a = 0; a < 3; ++a) {
            if (fabsf(gsa[a]) > 1e-9f) {
                float u = (-1.0f  - g0a[a]) / gsa[a];
                float v = (256.0f - g0a[a]) / gsa[a];
                raylo = fmaxf(raylo, fminf(u, v));
                rayhi = fminf(rayhi, fmaxf(u, v));
            } else if (!(g0a[a] > -1.0f && g0a[a] < 256.0f)) {
                raylo = 1e30f; rayhi = -1e30f;
            }
        }
    }
    // 1-sample safety margin, clamp to [0, 319]; this pixel's range is split
    // into 16 equal pieces -- chunk c walks the c-th piece.
    float a0 = fminf(fmaxf(raylo - 1.0f, 0.0f),  400.0f);
    float a1 = fminf(fmaxf(fminf(rayhi + 1.0f, (float)(NPTS - 1)), -1.0f), 400.0f);
    const int i0  = (int)ceilf(a0);
    const int i1  = (int)floorf(a1);
    const int len = max(0, i1 - i0 + 1);
    const int s0  = i0 + ((len * c) >> 4);
    const int s1  = i0 + ((len * (c + 1)) >> 4) - 1;

    float feat = 0.0f, Tc = 1.0f;   // Tc doubles as the opacity product (fp32-identical)

    for (int i = s0; i <= s1; ++i) {
        const float fi = (float)i;
        const float gx = fmaf(fi, gsx, g0x);
        const float gy = fmaf(fi, gsy, g0y);
        const float gz = fmaf(fi, gsz, g0z);
        const float xf = floorf(gx), yf = floorf(gy), zf = floorf(gz);
        const float fx = gx - xf, fy = gy - yf, fz = gz - zf;
        const int ix = (int)xf, iy = (int)yf, iz = (int)zf;

        if ((unsigned)ix <= 254u && (unsigned)iy <= 254u && (unsigned)iz <= 254u) {
            // fully inside: coverage == 1, dens == 0.1 exactly
            const float* b = vol + ((iz << 16) + (iy << 8) + ix);
            const float v000 = b[0],     v001 = b[1];
            const float v010 = b[256],   v011 = b[257];
            const float v100 = b[65536], v101 = b[65537];
            const float v110 = b[65792], v111 = b[65793];
            const float c00 = fmaf(fx, v001 - v000, v000);
            const float c01 = fmaf(fx, v011 - v010, v010);
            const float c10 = fmaf(fx, v101 - v100, v100);
            const float c11 = fmaf(fx, v111 - v110, v110);
            const float c0  = fmaf(fy, c01 - c00, c00);
            const float c1  = fmaf(fy, c11 - c10, c10);
            const float gray = fmaf(fz, c1 - c0, c0);
            feat = fmaf(0.1f * Tc, gray, feat);
            Tc *= 0.9f;
        } else {
            // boundary shell: masked weights, clamped indices
            const float wx0 = (ix >= 0  && ix <= 255) ? (1.0f - fx) : 0.0f;
            const float wx1 = (ix >= -1 && ix <= 254) ? fx          : 0.0f;
            const float wy0 = (iy >= 0  && iy <= 255) ? (1.0f - fy) : 0.0f;
            const float wy1 = (iy >= -1 && iy <= 254) ? fy          : 0.0f;
            const float wz0 = (iz >= 0  && iz <= 255) ? (1.0f - fz) : 0.0f;
            const float wz1 = (iz >= -1 && iz <= 254) ? fz          : 0.0f;
            const float cov = (wx0 + wx1) * (wy0 + wy1) * (wz0 + wz1);
            if (cov > 0.0f) {
                const int x0 = min(max(ix, 0), 255),   x1 = min(max(ix + 1, 0), 255);
                const int y0 = min(max(iy, 0), 255),   y1 = min(max(iy + 1, 0), 255);
                const int z0 = min(max(iz, 0), 255),   z1 = min(max(iz + 1, 0), 255);
                const float* bz0 = vol + (z0 << 16);
                const float* bz1 = vol + (z1 << 16);
                const int ry0 = y0 << 8, ry1 = y1 << 8;
                const float sv0 = (bz0[ry0 + x0]*wx0 + bz0[ry0 + x1]*wx1) * wy0
                                + (bz0[ry1 + x0]*wx0 + bz0[ry1 + x1]*wx1) * wy1;
                const float sv1 = (bz1[ry0 + x0]*wx0 + bz1[ry0 + x1]*wx1) * wy0
                                + (bz1[ry1 + x0]*wx0 + bz1[ry1 + x1]*wx1) * wy1;
                const float gray = sv0 * wz0 + sv1 * wz1;
                const float dens = 0.1f * cov;
                feat = fmaf(dens * Tc, gray, feat);
                Tc *= (1.0f - dens);
            }
        }
    }

    // combine the 16 depth chunks per pixel (ascending-depth partition):
    // feat = f0 + T0*(f1 + T1*(f2 + ...)),  T = T0*T1*...
    __shared__ float sf[CHUNKS][PX];
    __shared__ float sT[CHUNKS][PX];
    sf[c][p] = feat; sT[c][p] = Tc;
    __syncthreads();

    if (tid < PX) {
        float F = sf[CHUNKS - 1][p];
        #pragma unroll
        for (int j = CHUNKS - 2; j >= 0; --j) F = fmaf(sT[j][p], F, sf[j][p]);
        float PR = sT[0][p];
        #pragma unroll
        for (int j = 1; j < CHUNKS; ++j) PR *= sT[j][p];

        const float screen = fmaf(3.0f, F, 1.0f - PR) * 0.25f;
        outv[(w << 8) + h] = screen;   // transposed output layout

        float s = screen, s2 = screen * screen, mn = screen, mx = screen;
        #pragma unroll
        for (int o = 16; o; o >>= 1) {          // reduce across 32 lanes
            s  += __shfl_xor(s,  o);
            s2 += __shfl_xor(s2, o);
            mn  = fminf(mn, __shfl_xor(mn, o));
            mx  = fmaxf(mx, __shfl_xor(mx, o));
        }
        if (p == 0) {
            float4* out4 = (float4*)partials;
            out4[bid] = make_float4(s, s2, mn, mx);
        }
    }
}

// ---------------------------------------------------------------------------
// Normalize (finalize fused): every block redundantly reduces the 2048 block
// partials (32 KB, L2-hit) to {sum,sumsq,min,max}, derives the affine, and
// normalizes its 256 pixels.  out = (v - off) / (vmax - off),
// off = vmin - 1e-8*(std+1e-8)   (the mean cancels algebraically)
// ---------------------------------------------------------------------------
__global__ __launch_bounds__(256)
void xray_normalize(float* __restrict__ outv, const float* __restrict__ partials)
{
    const int t = threadIdx.x;
    const float4* p4 = (const float4*)partials;
    double s = 0.0, s2 = 0.0;
    float mn = 1e30f, mx = -1e30f;
    #pragma unroll
    for (int j = 0; j < NBLK / 256; ++j) {
        const float4 v = p4[j * 256 + t];
        s  += (double)v.x;
        s2 += (double)v.y;
        mn  = fminf(mn, v.z);
        mx  = fmaxf(mx, v.w);
    }
    #pragma unroll
    for (int o = 32; o; o >>= 1) {
        s  += __shfl_xor(s,  o);
        s2 += __shfl_xor(s2, o);
        mn  = fminf(mn, __shfl_xor(mn, o));
        mx  = fmaxf(mx, __shfl_xor(mx, o));
    }
    __shared__ double ls[4], ls2[4];
    __shared__ float  lmn[4], lmx[4];
    __shared__ float  soff, sinv;
    const int wid = t >> 6, lane = t & 63;
    if (lane == 0) { ls[wid] = s; ls2[wid] = s2; lmn[wid] = mn; lmx[wid] = mx; }
    __syncthreads();
    if (t == 0) {
        const double S  = ls[0] + ls[1] + ls[2] + ls[3];
        const double S2 = ls2[0] + ls2[1] + ls2[2] + ls2[3];
        const float MN = fminf(fminf(lmn[0], lmn[1]), fminf(lmn[2], lmn[3]));
        const float MX = fmaxf(fmaxf(lmx[0], lmx[1]), fmaxf(lmx[2], lmx[3]));
        double var = (S2 - S * S / 65536.0) / 65535.0;
        if (var < 0.0) var = 0.0;
        const double sdp = sqrt(var) + 1e-8;
        const float off = MN - (float)(1e-8 * sdp);
        soff = off;
        sinv = 1.0f / (MX - off);
    }
    __syncthreads();
    const int i = blockIdx.x * 256 + t;
    outv[i] = (outv[i] - soff) * sinv;
}

// ---------------------------------------------------------------------------
extern "C" void kernel_launch(void* const* d_in, const int* in_sizes, int n_in,
                              void* d_out, int out_size, void* d_ws, size_t ws_size,
                              hipStream_t stream)
{
    const float* vol = (const float*)d_in[0];   // (1,1,256,256,256)
    const float* Rm  = (const float*)d_in[1];   // (1,3,3)
    const float* Tv  = (const float*)d_in[2];   // (1,3)
    const float* fc  = (const float*)d_in[3];   // (1,)
    float* outv = (float*)d_out;                // (1,1,256,256) fp32
    float* partials = (float*)d_ws;             // 2048 float4

    xray_render<<<NBLK, 512, 0, stream>>>(vol, Rm, Tv, fc, outv, partials);
    xray_normalize<<<IMG * IMG / 256, 256, 0, stream>>>(outv, partials);
}